// Round 9
// baseline (57.145 us; speedup 1.0000x reference)
//
#include <hip/hip_runtime.h>
#include <hip/hip_bf16.h>
#include <stdint.h>

typedef __bf16 bf16x8 __attribute__((ext_vector_type(8)));
typedef float  f32x4  __attribute__((ext_vector_type(4)));

#define LOG2E   1.4426950408889634f
#define LN2     0.6931471805599453f
#define C_SCALED 86.56170245f   // 60*log2(e); cancels in log2(S)-diag', kept for fp range

__device__ __forceinline__ void gload_lds16(const void* gsrc, void* ldst) {
    __builtin_amdgcn_global_load_lds(
        (const __attribute__((address_space(1))) unsigned int*)gsrc,
        (__attribute__((address_space(3))) unsigned int*)ldst,
        16, 0, 0);
}

// ---------------- kernel 1: permute + fp32->bf16 ----------------
// pred[b][n][c][h][w] -> A[m][c] row-major, SCALED by log2(e). gt -> B[m][c].
__global__ void convert_perm(const float* __restrict__ pred, const float* __restrict__ gt,
                             __bf16* __restrict__ Ab, __bf16* __restrict__ Bb)
{
    __shared__ __bf16 tile[256 * 17];
    const int slab = blockIdx.x & 511;
    const bool isA = blockIdx.x < 512;
    const float scale = isA ? LOG2E : 1.0f;
    const float* src = (isA ? pred : gt) + (size_t)slab * 4096;
    __bf16* dst = (isA ? Ab : Bb) + (size_t)slab * 4096;
    const int t = threadIdx.x;
    #pragma unroll
    for (int it = 0; it < 16; ++it) {
        const int e = it * 256 + t;          // c = e>>4, hw = e&15
        tile[(e >> 4) * 17 + (e & 15)] = (__bf16)(src[e] * scale);
    }
    __syncthreads();
    #pragma unroll
    for (int it = 0; it < 16; ++it) {
        const int o = it * 256 + t;          // hw = o>>8, c = o&255
        dst[(o >> 8) * 256 + (o & 255)] = tile[(o & 255) * 17 + (o >> 8)];
    }
}

// ---------------- kernel 2: fused GEMM + exp2-sum + diag ----------------
// ONE 8-wave block per CU (512 thr), tile 512i x 512j, grid 256. Each wave
// owns 64 i-rows in regs (pfr 128). B dbuf in LDS (2x32KB). Per 64j step:
// 1 barrier; waves 0-3 process bands (0,1,2,3), waves 4-7 process (2,3,0,1)
// -> same-SIMD wave pairs are ANTI-PHASED: one runs MFMA while its mate
// runs EP/reads. acc is MFMA-C-initialized to -C_SCALED (kills all EP subs).
__global__ __launch_bounds__(512) __attribute__((amdgpu_waves_per_eu(2, 2)))
void gemm_lse(const __bf16* __restrict__ Ab, const __bf16* __restrict__ Bb,
              float* __restrict__ rowsum_part, float* __restrict__ diagy)
{
    __shared__ __align__(16) char lds[65536];   // two 32KB B buffers
    const int tid  = threadIdx.x;
    const int lane = tid & 63;
    const int w    = tid >> 6;       // 0..7 (i split: 64 rows each)
    const int l15  = lane & 15;
    const int lhi  = lane >> 4;

    const int jc = blockIdx.x & 15;  // same-jc blocks are 16 apart -> same XCD
    const int ib = blockIdx.x >> 4;  // 16 i-blocks of 512
    const int i0 = ib << 9;
    const int j0 = jc << 9;

    // ---- A fragments: 64 i-rows/wave, K=256 -> 4ii x 8ks bf16x8 (128 regs) ----
    bf16x8 pfr[4][8];
    {
        const char* base = (const char*)Ab + (size_t)(i0 + w * 64 + l15) * 512 + lhi * 16;
        #pragma unroll
        for (int ii = 0; ii < 4; ++ii)
            #pragma unroll
            for (int ks = 0; ks < 8; ++ks)
                pfr[ii][ks] = *(const bf16x8*)(base + ii * 16 * 512 + ks * 64);
    }

    const char* Bbase = (const char*)Bb + (size_t)j0 * 512;
    const int   rsw   = l15 << 4;            // read-side XOR swizzle
    const int   colb  = lhi * 16;
    const int   ibase = i0 + w * 64;

    // prologue stage of step 0: 512 thr x 4 x 16B = 32KB
    #pragma unroll
    for (int it = 0; it < 4; ++it) {
        const int ob = it * 8192 + w * 1024;
        const int ol = ob + lane * 16;
        const int sb = ol ^ (((ol >> 9) & 15) << 4);
        gload_lds16(Bbase + sb, lds + ob);
    }

    float rs[4] = {0.f, 0.f, 0.f, 0.f};

#define READ8(G, BAND) { \
    const char* rp_ = bufp + ((BAND) * 16 + l15) * 512; \
    _Pragma("unroll") \
    for (int ks_ = 0; ks_ < 8; ++ks_) \
        G[ks_] = *(const bf16x8*)(rp_ + ((ks_ * 64 + colb) ^ rsw)); }

#define READ4(G, BAND, H) { \
    const char* rp_ = bufp + ((BAND) * 16 + l15) * 512; \
    _Pragma("unroll") \
    for (int k_ = 0; k_ < 4; ++k_) \
        G[(H) * 4 + k_] = *(const bf16x8*)(rp_ + ((((H) * 4 + k_) * 64 + colb) ^ rsw)); }

#define MM16(G, H) { \
    __builtin_amdgcn_s_setprio(1); \
    _Pragma("unroll") \
    for (int k_ = 0; k_ < 4; ++k_) { \
        const int ks_ = (H) * 4 + k_; \
        _Pragma("unroll") \
        for (int ii_ = 0; ii_ < 4; ++ii_) \
            acc[ii_] = __builtin_amdgcn_mfma_f32_16x16x32_bf16( \
                G[ks_], pfr[ii_][ks_], acc[ii_], 0, 0, 0); \
    } \
    __builtin_amdgcn_s_setprio(0); }

// MFMA C-operand carries the -C_SCALED offset: no subtract in EP.
#define ZEROACC() { _Pragma("unroll") for (int ii_ = 0; ii_ < 4; ++ii_) \
    acc[ii_] = (f32x4){-C_SCALED, -C_SCALED, -C_SCALED, -C_SCALED}; }

#define EP(JJ) { \
    const int jb_ = jbase + (JJ) * 16; \
    _Pragma("unroll") \
    for (int ii_ = 0; ii_ < 4; ++ii_) { \
        const f32x4 a_ = acc[ii_]; \
        float s_ = __builtin_amdgcn_exp2f(a_[0]) + __builtin_amdgcn_exp2f(a_[1]); \
        s_ += __builtin_amdgcn_exp2f(a_[2]) + __builtin_amdgcn_exp2f(a_[3]); \
        if (ibase + ii_ * 16 == jb_) { \
            const int ig_ = ibase + ii_ * 16 + l15; \
            const int rb_ = lhi * 4; \
            if (l15 == rb_ + 0) diagy[ig_] = a_[0]; \
            if (l15 == rb_ + 1) diagy[ig_] = a_[1]; \
            if (l15 == rb_ + 2) diagy[ig_] = a_[2]; \
            if (l15 == rb_ + 3) diagy[ig_] = a_[3]; \
        } \
        rs[ii_] += s_; \
    } }

#define STAGE_NEXT() { \
    _Pragma("unroll") \
    for (int it_ = 0; it_ < 4; ++it_) { \
        const int ob_ = it_ * 8192 + w * 1024; \
        const int ol_ = ob_ + lane * 16; \
        const int sb_ = ol_ ^ (((ol_ >> 9) & 15) << 4); \
        gload_lds16(nsrc + sb_, nbuf + ob_); \
    } }

#define STEP_SEQ(B0, B1, B2, B3) { \
    bf16x8 g[8], h[8]; f32x4 acc[4]; \
    READ8(g, B0); \
    if (js < 7) STAGE_NEXT(); \
    ZEROACC(); READ4(h, B1, 0); MM16(g, 0); READ4(h, B1, 1); MM16(g, 1); EP(B0); \
    ZEROACC(); READ4(g, B2, 0); MM16(h, 0); READ4(g, B2, 1); MM16(h, 1); EP(B1); \
    ZEROACC(); READ4(h, B3, 0); MM16(g, 0); READ4(h, B3, 1); MM16(g, 1); EP(B2); \
    ZEROACC();                  MM16(h, 0);                  MM16(h, 1); EP(B3); }

    const bool lowHalf = (w < 4);   // wave-pair anti-phase: w and w+4 share a SIMD

    for (int js = 0; js < 8; ++js) {
        asm volatile("s_waitcnt vmcnt(0)" ::: "memory");  // stage loads (1 step old) landed
        __builtin_amdgcn_s_barrier();                     // the ONLY barrier per step

        const char* bufp  = lds + (js & 1) * 32768;
        char*       nbuf  = lds + ((js + 1) & 1) * 32768;
        const char* nsrc  = Bbase + (size_t)(js + 1) * 32768;
        const int   jbase = j0 + js * 64;

        if (lowHalf) { STEP_SEQ(0, 1, 2, 3); }
        else         { STEP_SEQ(2, 3, 0, 1); }
    }

#undef READ8
#undef READ4
#undef MM16
#undef ZEROACC
#undef EP
#undef STAGE_NEXT
#undef STEP_SEQ

    // reduce partials across the 4 lhi groups; store to [i][slice=jc] layout
    #pragma unroll
    for (int ii = 0; ii < 4; ++ii) {
        float v = rs[ii];
        v += __shfl_xor(v, 16);
        v += __shfl_xor(v, 32);
        if (lhi == 0)
            rowsum_part[(size_t)(i0 + w * 64 + ii * 16 + l15) * 16 + jc] = v;
    }
}

// ---------------- kernel 3: single-block final reduce ----------------
// val_i = log2(sum_jc part[i][jc]) - diag'_i ; loss = ln2 * mean(val)
__global__ __launch_bounds__(1024) void reduce_final(const float* __restrict__ rowsum_part,
                                                     const float* __restrict__ diagy,
                                                     float* __restrict__ out)
{
    float v = 0.f;
    #pragma unroll
    for (int r = 0; r < 8; ++r) {
        const int i = r * 1024 + threadIdx.x;
        const f32x4* p = (const f32x4*)(rowsum_part + (size_t)i * 16);
        float s = 0.f;
        #pragma unroll
        for (int k = 0; k < 4; ++k) {
            const f32x4 t = p[k];
            s += (t[0] + t[1]) + (t[2] + t[3]);
        }
        v += __log2f(s) - diagy[i];
    }
    #pragma unroll
    for (int d = 1; d < 64; d <<= 1) v += __shfl_xor(v, d);
    __shared__ float red[16];
    if ((threadIdx.x & 63) == 0) red[threadIdx.x >> 6] = v;
    __syncthreads();
    if (threadIdx.x == 0) {
        float t = 0.f;
        #pragma unroll
        for (int k = 0; k < 16; ++k) t += red[k];
        out[0] = LN2 * t * (1.0f / 8192.0f);
    }
}

// ---------------- launch ----------------
extern "C" void kernel_launch(void* const* d_in, const int* in_sizes, int n_in,
                              void* d_out, int out_size, void* d_ws, size_t ws_size,
                              hipStream_t stream) {
    const float* pred = (const float*)d_in[0];
    const float* gt   = (const float*)d_in[1];
    float* out = (float*)d_out;

    char* ws = (char*)d_ws;
    float*  diagy       = (float*)(ws + 0x1000);    // 8192 f32 (fully overwritten)
    float*  rowsum_part = (float*)(ws + 0x10000);   // 8192 x 16 f32 = 512KB (fully written)
    __bf16* Ab          = (__bf16*)(ws + 0x100000); // 4MB
    __bf16* Bb          = (__bf16*)(ws + 0x500000); // 4MB

    convert_perm<<<1024, 256, 0, stream>>>(pred, gt, Ab, Bb);
    gemm_lse<<<256, 512, 0, stream>>>(Ab, Bb, rowsum_part, diagy);
    reduce_final<<<1, 1024, 0, stream>>>(rowsum_part, diagy, out);
}